// Round 13
// baseline (235.448 us; speedup 1.0000x reference)
//
#include <hip/hip_runtime.h>

// Trajectron sliding-window LSTM embed:
//   inputs [T=256, B=128, N=4, D=2] f32
//   his LSTM H=32 over n=3; int LSTM H=8 over n=0; window 64 ending at t
//   out[t,b,:] = [h_his | h_int] @ W_out.T + b_out   -> [256,128,2] f32
//
// Round-13: single fused MFMA kernel. R12's his_kernel (103us) + int_kernel
// + prep + 3-launch serialization = 209us total; this round folds the int
// LSTM into the his waves as 2 extra MFMA tiles (K zero-padded 8->32):
//   - int rows permuted so lane n<8 holds (i,f) of unit n, n>=8 holds (g,o)
//   - activate own gates, exchange via 2 shfl_xor(8), compute c,h
//     redundantly on the lane pair (R11-verified)
//   - int h: 256B LDS region, written by n<8 lanes, read as A-frag by quad0
// Kills the int kernel, eInt buffer and one launch; the int work's
// independent dep-chain fills the his wave's latency gaps (free ILP).
// his path is R12 verbatim (correctness-verified, absmax 4.9e-4).

typedef float v4f __attribute__((ext_vector_type(4)));
typedef _Float16 h8v __attribute__((ext_vector_type(8)));

static __device__ __forceinline__ float fexp2(float x) {
    return __builtin_amdgcn_exp2f(x);
}
static __device__ __forceinline__ float frcp(float x) {
    return __builtin_amdgcn_rcpf(x);
}
static __device__ __forceinline__ unsigned short f2h(float f) {
    _Float16 h = (_Float16)f;
    unsigned short u;
    __builtin_memcpy(&u, &h, 2);
    return u;
}

#define LOG2E    1.442695041f
#define TWOLOG2E 2.885390082f

// ws layout:
//   float [5120,5248)  hisBP : permuted-prescaled his bias, index p
//   float [5376,5632)  hisXP : permuted-prescaled his Wih, 2p+{0,1}
//   ushort[11776,15872) hisWH: fp16 permuted-prescaled Whh_his [128][32]
//   float [8192,8224)  intBP : permuted-prescaled int bias, index p2
//   float [8224,8288)  intXP : permuted-prescaled int Wih, 2*p2+{0,1}
//   ushort[16640,17664) intWH: fp16 permuted-prescaled Whh_int [32][32],
//                              k>=8 zero-padded
// his permutation p = T*16+n -> row r = (T>>1)*32 + 2n + (T&1)
//   (tiles 0,1=i 2,3=f 4,5=g 6,7=o; even tile -> unit 2n)
// int permutation p2 = t*16+n:
//   t0: n<8 -> i-row n     | n>=8 -> g-row (n-8)  [r2 = n | n+8]
//   t1: n<8 -> f-row n     | n>=8 -> o-row (n-8)  [r2 = n+8 | n+16]
// scale s = -log2e (sigmoid rows) / -2log2e (g rows)
__global__ __launch_bounds__(256) void prep_kernel(
    const float* __restrict__ Wih_his, const float* __restrict__ Whh_his,
    const float* __restrict__ bih_his, const float* __restrict__ bhh_his,
    const float* __restrict__ Wih_int, const float* __restrict__ Whh_int,
    const float* __restrict__ bih_int, const float* __restrict__ bhh_int,
    float* __restrict__ ws)
{
    const int i = blockIdx.x * 256 + threadIdx.x;
    unsigned short* wsu = reinterpret_cast<unsigned short*>(ws);
    if (i < 128) {                      // hisBP
        const int p = i;
        const int T = p >> 4, n = p & 15;
        const int gi = T >> 1, u = 2 * n + (T & 1);
        const int r = gi * 32 + u;
        const float s = (gi == 2) ? -TWOLOG2E : -LOG2E;
        ws[5120 + p] = (bih_his[r] + bhh_his[r]) * s;
    } else if (i < 384) {               // hisXP
        const int e = i - 128;
        const int p = e >> 1, comp = e & 1;
        const int T = p >> 4, n = p & 15;
        const int gi = T >> 1, u = 2 * n + (T & 1);
        const int r = gi * 32 + u;
        const float s = (gi == 2) ? -TWOLOG2E : -LOG2E;
        ws[5376 + e] = Wih_his[r * 2 + comp] * s;
    } else if (i < 4480) {              // hisWH (fp16)
        const int e = i - 384;
        const int p = e >> 5, k = e & 31;
        const int T = p >> 4, n = p & 15;
        const int gi = T >> 1, u = 2 * n + (T & 1);
        const int r = gi * 32 + u;
        const float s = (gi == 2) ? -TWOLOG2E : -LOG2E;
        wsu[11776 + e] = f2h(Whh_his[r * 32 + k] * s);
    } else if (i < 4512) {              // intBP
        const int p2 = i - 4480;
        const int t = p2 >> 4, n = p2 & 15;
        const int r2 = (t == 0) ? ((n < 8) ? n : n + 8)
                                : ((n < 8) ? n + 8 : n + 16);
        const float s = (r2 >= 16 && r2 < 24) ? -TWOLOG2E : -LOG2E;
        ws[8192 + p2] = (bih_int[r2] + bhh_int[r2]) * s;
    } else if (i < 4576) {              // intXP
        const int e = i - 4512;
        const int p2 = e >> 1, comp = e & 1;
        const int t = p2 >> 4, n = p2 & 15;
        const int r2 = (t == 0) ? ((n < 8) ? n : n + 8)
                                : ((n < 8) ? n + 8 : n + 16);
        const float s = (r2 >= 16 && r2 < 24) ? -TWOLOG2E : -LOG2E;
        ws[8224 + e] = Wih_int[r2 * 2 + comp] * s;
    } else if (i < 5600) {              // intWH (fp16, k>=8 zero)
        const int e = i - 4576;
        const int p2 = e >> 5, k = e & 31;
        const int t = p2 >> 4, n = p2 & 15;
        const int r2 = (t == 0) ? ((n < 8) ? n : n + 8)
                                : ((n < 8) ? n + 8 : n + 16);
        const float s = (r2 >= 16 && r2 < 24) ? -TWOLOG2E : -LOG2E;
        wsu[16640 + e] = (k < 8) ? f2h(Whh_int[r2 * 8 + k] * s)
                                 : (unsigned short)0;
    }
}

// ---------- fused his+int LSTM: 16 chains per wave via MFMA ---------------
__global__ __launch_bounds__(64) void traj_kernel(
    const float* __restrict__ inp, const float* __restrict__ ws,
    const float* __restrict__ W_out, const float* __restrict__ b_out,
    float* __restrict__ out)
{
    __shared__ __align__(16) unsigned short hm[2][16][40];   // his h (fp16)
    __shared__ __align__(16) unsigned short hmI[2][16][8];   // int h (fp16)

    const int lane = threadIdx.x;
    const int n    = lane & 15;
    const int quad = lane >> 4;
    const int Wd   = blockIdx.x;               // 0..2047
    const int t    = Wd >> 3;                  // uniform per wave
    const int bg   = Wd & 7;                   // chains bg*16 .. +15
    const int nsteps = (t >= 63) ? 64 : (t + 1);
    const int tau0   = (t >= 63) ? (t - 63) : 0;
    const bool lo  = (n < 8);

    // B-frags: his 8 tiles + int 2 tiles (row p*32 ushorts, k=quad*8..)
    h8v Bf[8], BfI[2];
    {
        const h8v* wb = reinterpret_cast<const h8v*>(
            reinterpret_cast<const unsigned short*>(ws) + 11776);
#pragma unroll
        for (int T = 0; T < 8; ++T) Bf[T] = wb[(T * 16 + n) * 4 + quad];
        const h8v* wbI = reinterpret_cast<const h8v*>(
            reinterpret_cast<const unsigned short*>(ws) + 16640);
#pragma unroll
        for (int T = 0; T < 2; ++T) BfI[T] = wbI[(T * 16 + n) * 4 + quad];
    }
    // C-init constants (x-part)
    float cb[8], cw0[8], cw1[8], cbI[2], cwI0[2], cwI1[2];
#pragma unroll
    for (int T = 0; T < 8; ++T) {
        const int p = T * 16 + n;
        cb[T]  = ws[5120 + p];
        cw0[T] = ws[5376 + 2 * p];
        cw1[T] = ws[5376 + 2 * p + 1];
    }
#pragma unroll
    for (int T = 0; T < 2; ++T) {
        const int p2 = T * 16 + n;
        cbI[T]  = ws[8192 + p2];
        cwI0[T] = ws[8224 + 2 * p2];
        cwI1[T] = ws[8224 + 2 * p2 + 1];
    }

    // x for this lane's 4 chains (quad*4+r): his slot n=3 (+6), int n=0 (+0)
    const int bbase = bg * 16 + quad * 4;
    const float* xpB = inp + tau0 * 1024 + bbase * 8;
    float2 xc[4], xcI[4];
#pragma unroll
    for (int r = 0; r < 4; ++r) {
        xc[r]  = *reinterpret_cast<const float2*>(xpB + r * 8 + 6);
        xcI[r] = *reinterpret_cast<const float2*>(xpB + r * 8);
    }
    xpB += 1024;

    h8v Af = {}, Afi = {};               // h = 0 (Afi quads 1-3 stay 0)
    float cs[4][2] = {}, csI[4] = {};
    float h0[4] = {}, h1[4] = {}, hI[4] = {};

#pragma unroll 1
    for (int s = 0; s < nsteps; ++s) {
        float2 xn[4], xnI[4];
        if (s + 1 < nsteps) {               // wave-uniform branch
#pragma unroll
            for (int r = 0; r < 4; ++r) {
                xn[r]  = *reinterpret_cast<const float2*>(xpB + r * 8 + 6);
                xnI[r] = *reinterpret_cast<const float2*>(xpB + r * 8);
            }
        } else {
#pragma unroll
            for (int r = 0; r < 4; ++r) {
                xn[r] = make_float2(0.f, 0.f);
                xnI[r] = make_float2(0.f, 0.f);
            }
        }
        xpB += 1024;

        // ---- his: 8 MFMAs  D[T] = H @ WhhP_T + (Wih x + b) ----
        v4f D[8];
#pragma unroll
        for (int T = 0; T < 8; ++T) {
            v4f C;
#pragma unroll
            for (int r = 0; r < 4; ++r)
                C[r] = fmaf(cw1[T], xc[r].y, fmaf(cw0[T], xc[r].x, cb[T]));
            D[T] = __builtin_amdgcn_mfma_f32_16x16x32_f16(Af, Bf[T], C, 0, 0, 0);
        }
        // ---- int: 2 MFMAs ----
        v4f DI[2];
#pragma unroll
        for (int T = 0; T < 2; ++T) {
            v4f C;
#pragma unroll
            for (int r = 0; r < 4; ++r)
                C[r] = fmaf(cwI1[T], xcI[r].y, fmaf(cwI0[T], xcI[r].x, cbI[T]));
            DI[T] = __builtin_amdgcn_mfma_f32_16x16x32_f16(Afi, BfI[T], C, 0, 0, 0);
        }

        // ---- his activations (R12 verbatim): 4 chains x units {2n,2n+1} --
#pragma unroll
        for (int r = 0; r < 4; ++r) {
            {
                const float si = frcp(1.f + fexp2(D[0][r]));
                const float sf = frcp(1.f + fexp2(D[2][r]));
                const float tg = fmaf(2.f, frcp(1.f + fexp2(D[4][r])), -1.f);
                const float so = frcp(1.f + fexp2(D[6][r]));
                const float cn = fmaf(sf, cs[r][0], si * tg);
                cs[r][0] = cn;
                h0[r] = so * fmaf(-2.f, frcp(1.f + fexp2(TWOLOG2E * cn)), 1.f);
            }
            {
                const float si = frcp(1.f + fexp2(D[1][r]));
                const float sf = frcp(1.f + fexp2(D[3][r]));
                const float tg = fmaf(2.f, frcp(1.f + fexp2(D[5][r])), -1.f);
                const float so = frcp(1.f + fexp2(D[7][r]));
                const float cn = fmaf(sf, cs[r][1], si * tg);
                cs[r][1] = cn;
                h1[r] = so * fmaf(-2.f, frcp(1.f + fexp2(TWOLOG2E * cn)), 1.f);
            }
        }

        // ---- int activations: own gates, pair-exchange, redundant c,h ----
        // lane n<8 owns (i,f) of unit n; n>=8 owns (g,o) of unit n-8
#pragma unroll
        for (int r = 0; r < 4; ++r) {
            const float r0 = frcp(1.f + fexp2(DI[0][r]));
            const float v0 = lo ? r0 : fmaf(2.f, r0, -1.f);  // sig(i)|tanh(g)
            const float v1 = frcp(1.f + fexp2(DI[1][r]));    // sig(f)|sig(o)
            const float o0 = __shfl_xor(v0, 8);
            const float o1 = __shfl_xor(v1, 8);
            const float gi = lo ? v0 : o0;
            const float gf = lo ? v1 : o1;
            const float gg = lo ? o0 : v0;
            const float go = lo ? o1 : v1;
            const float cn = fmaf(gf, csI[r], gi * gg);
            csI[r] = cn;
            hI[r] = go * fmaf(-2.f, frcp(1.f + fexp2(TWOLOG2E * cn)), 1.f);
        }

        // ---- transpose h back to A-layout (skip last step) ----
        if (s + 1 < nsteps) {
            const int bf = s & 1;
#pragma unroll
            for (int r = 0; r < 4; ++r) {
                const unsigned pk =
                    ((unsigned)f2h(h1[r]) << 16) | f2h(h0[r]);
                *reinterpret_cast<unsigned*>(&hm[bf][quad * 4 + r][2 * n]) = pk;
            }
            if (lo) {
#pragma unroll
                for (int r = 0; r < 4; ++r)
                    hmI[bf][quad * 4 + r][n] = f2h(hI[r]);
            }
            __builtin_amdgcn_wave_barrier();
            asm volatile("s_waitcnt lgkmcnt(0)" ::: "memory");
            __builtin_amdgcn_wave_barrier();
            Af = *reinterpret_cast<const h8v*>(&hm[bf][n][quad * 8]);
            if (quad == 0)
                Afi = *reinterpret_cast<const h8v*>(&hmI[bf][n][0]);
        }

#pragma unroll
        for (int r = 0; r < 4; ++r) { xc[r] = xn[r]; xcI[r] = xnI[r]; }
    }

    // ---- projection: his units {2n,2n+1} + int unit n (n<8 only, once) ---
    const float wo0a = W_out[2 * n],      wo0b = W_out[2 * n + 1];
    const float wo1a = W_out[40 + 2 * n], wo1b = W_out[40 + 2 * n + 1];
    float e0[4], e1[4];
#pragma unroll
    for (int r = 0; r < 4; ++r) {
        e0[r] = fmaf(wo0b, h1[r], wo0a * h0[r]);
        e1[r] = fmaf(wo1b, h1[r], wo1a * h0[r]);
        if (lo) {
            e0[r] = fmaf(W_out[32 + n], hI[r], e0[r]);
            e1[r] = fmaf(W_out[72 + n], hI[r], e1[r]);
        }
#pragma unroll
        for (int m = 1; m <= 8; m <<= 1) {
            e0[r] += __shfl_xor(e0[r], m);
            e1[r] += __shfl_xor(e1[r], m);
        }
    }
    if (n == 0) {
        const float bo0 = b_out[0], bo1 = b_out[1];
#pragma unroll
        for (int r = 0; r < 4; ++r) {
            const int chain = t * 128 + bbase + r;
            float2 o;
            o.x = e0[r] + bo0;
            o.y = e1[r] + bo1;
            reinterpret_cast<float2*>(out)[chain] = o;
        }
    }
}

extern "C" void kernel_launch(void* const* d_in, const int* in_sizes, int n_in,
                              void* d_out, int out_size, void* d_ws, size_t ws_size,
                              hipStream_t stream) {
    const float* inp     = (const float*)d_in[0];
    const float* Wih_his = (const float*)d_in[1];
    const float* Whh_his = (const float*)d_in[2];
    const float* bih_his = (const float*)d_in[3];
    const float* bhh_his = (const float*)d_in[4];
    const float* Wih_int = (const float*)d_in[5];
    const float* Whh_int = (const float*)d_in[6];
    const float* bih_int = (const float*)d_in[7];
    const float* bhh_int = (const float*)d_in[8];
    const float* W_out   = (const float*)d_in[9];
    const float* b_out   = (const float*)d_in[10];
    float* out = (float*)d_out;
    float* ws  = (float*)d_ws;

    // pre-pass: prescale + permute weights (his + int fp16 MFMA tiles)
    prep_kernel<<<dim3(22), dim3(256), 0, stream>>>(
        Wih_his, Whh_his, bih_his, bhh_his,
        Wih_int, Whh_int, bih_int, bhh_int, ws);

    // fused his+int: 2048 waves, 16 chains each, 10 MFMAs per step
    traj_kernel<<<dim3(2048), dim3(64), 0, stream>>>(
        inp, ws, W_out, b_out, out);
}